// Round 4
// baseline (122.194 us; speedup 1.0000x reference)
//
#include <hip/hip_runtime.h>

// ---------------------------------------------------------------------------
// Fast math helpers.
// ---------------------------------------------------------------------------
__device__ __forceinline__ float fast_exp(float x) {
  return __builtin_amdgcn_exp2f(x * 1.4426950408889634f);
}
__device__ __forceinline__ float fast_rcp(float x) {
  return __builtin_amdgcn_rcpf(x);
}
__device__ __forceinline__ float fast_cos(float x) {
  // v_cos takes revolutions; v_fract does the range reduction.
  return __builtin_amdgcn_cosf(__builtin_amdgcn_fractf(x * 0.15915494309189535f));
}
__device__ __forceinline__ float fast_sigmoid(float x) {
  return fast_rcp(1.0f + fast_exp(-x));
}
__device__ __forceinline__ float fast_tanh(float x) {
  return 1.0f - 2.0f * fast_rcp(1.0f + fast_exp(2.0f * x));
}
// sigmoid on [-1,1]: 0.5 + x/4 - x^3/48 + x^5/480 - 17x^7/80640 (err ~2e-5)
__device__ __forceinline__ float sigmoid_poly(float x) {
  float x2 = x * x;
  float p = fmaf(fmaf(fmaf(-2.1085373e-4f, x2, 2.0833334e-3f), x2,
                      -2.0833334e-2f), x2, 0.25f);
  return fmaf(x, p, 0.5f);
}
// tanh Pade(5,4): err <1e-6 @|x|<=1, <1.3e-4 @|x|<=2.5 (cell state bound ~2.1)
__device__ __forceinline__ float tanh_pade(float x) {
  float x2 = x * x;
  float num = x * fmaf(x2 + 105.f, x2, 945.f);
  float den = fmaf(fmaf(15.f, x2, 420.f), x2, 945.f);
  return num * fast_rcp(den);
}

// Cross-lane XOR exchange via ds_swizzle (BitMode: offset=(xor<<10)|0x1F).
// Single DS instruction, all-lane pull semantics: dst[i] = src[i ^ XORM].
template <int PAT>
__device__ __forceinline__ float swzf(float v) {
  return __int_as_float(__builtin_amdgcn_ds_swizzle(__float_as_int(v), PAT));
}
#define SWZ_XOR1 0x041F
#define SWZ_XOR2 0x081F
#define SWZ_XOR3 0x0C1F

// ---------------------------------------------------------------------------
// Kernel 1: precompute x-part of gate activations, LDS-staged for coalescing.
//   Z[t][j][b][g] = x[t,b,:] . W_g[row_j, :D] + fold   (j in {0,1,2} -> linear
// rows {0,1,3}; row 2 is dead: RZ on |0> is a global phase). fold = bias+theta
// for rows 0,3.  Register-prefetch of chunk kc+1 overlaps compute of kc.
// ---------------------------------------------------------------------------
__global__ __launch_bounds__(256) void qlstm_gemm(
    const float* __restrict__ x,
    const float* __restrict__ Wf, const float* __restrict__ bf,
    const float* __restrict__ Wi, const float* __restrict__ bi,
    const float* __restrict__ Wu, const float* __restrict__ bu,
    const float* __restrict__ Wo, const float* __restrict__ bo,
    const float* __restrict__ thf, const float* __restrict__ thi,
    const float* __restrict__ thu, const float* __restrict__ tho,
    float* __restrict__ Z, long long rows, int B, int D)
{
  __shared__ float tile[256][36];  // LD=36: 2-way bank aliasing only (free)
  const long long base = (long long)blockIdx.x * 256;
  const int tid = threadIdx.x;
  const long long r = base + tid;
  const bool valid = r < rows;
  const int ldw = D + 4;
  const float* Ws[4] = {Wf, Wi, Wu, Wo};
  const float* bs[4] = {bf, bi, bu, bo};
  const float* ts[4] = {thf, thi, thu, tho};

  float acc[12];
#pragma unroll
  for (int g = 0; g < 4; ++g) {
    acc[g * 3 + 0] = bs[g][0] + ts[g][0];  // theta0 folded
    acc[g * 3 + 1] = bs[g][1];
    acc[g * 3 + 2] = bs[g][3] + ts[g][3];  // theta3 folded
  }

  // this thread's 2 staging loads: rows base+(tid>>3)*... (8 threads/row of 32)
  const int srow0 = (tid * 4) >> 5;        // rows 0..31 (i=0..7 adds 32 each)
  const int scol  = (tid * 4) & 31;
  const int nkc = D >> 5;  // D multiple of 32 (D=128)

  float4 pf[8];
  // prefetch kc = 0
#pragma unroll
  for (int i = 0; i < 8; ++i) {
    long long gr = base + srow0 + i * 32;
    if (gr < rows) pf[i] = *(const float4*)(x + gr * (long long)D + scol);
  }

  for (int kc = 0; kc < nkc; ++kc) {
#pragma unroll
    for (int i = 0; i < 8; ++i)
      *(float4*)&tile[srow0 + i * 32][scol] = pf[i];
    __syncthreads();
    if (kc + 1 < nkc) {  // prefetch next chunk while computing this one
#pragma unroll
      for (int i = 0; i < 8; ++i) {
        long long gr = base + srow0 + i * 32;
        if (gr < rows)
          pf[i] = *(const float4*)(x + gr * (long long)D + (kc + 1) * 32 + scol);
      }
    }
    if (valid) {
#pragma unroll
      for (int k = 0; k < 32; k += 4) {
        float4 xv = *(float4*)&tile[tid][k];
#pragma unroll
        for (int g = 0; g < 4; ++g) {
#pragma unroll
          for (int jj = 0; jj < 3; ++jj) {
            int row2 = (jj == 2) ? 3 : jj;
            const float* wp = Ws[g] + row2 * ldw + kc * 32 + k;  // uniform -> s_load
            acc[g * 3 + jj] += xv.x * wp[0] + xv.y * wp[1] + xv.z * wp[2] + xv.w * wp[3];
          }
        }
      }
    }
    __syncthreads();
  }

  if (valid) {
    long long t = r / B;
    int b = (int)(r - t * B);
    float4 s0 = make_float4(acc[0], acc[3], acc[6], acc[9]);   // a0 per gate
    float4 s1 = make_float4(acc[1], acc[4], acc[7], acc[10]);  // a1 per gate
    float4 s2 = make_float4(acc[2], acc[5], acc[8], acc[11]);  // a3 per gate
    *(float4*)(Z + ((t * 3 + 0) * (long long)B + b) * 4) = s0;
    *(float4*)(Z + ((t * 3 + 1) * (long long)B + b) * 4) = s1;
    *(float4*)(Z + ((t * 3 + 2) * (long long)B + b) * 4) = s2;
  }
}

// ---------------------------------------------------------------------------
// Kernel 2: scan with 4 lanes per batch element (lane q = gate q; after the
// 4x4 quad transpose lane q = component q). Cross-lane via ds_swizzle only.
// ---------------------------------------------------------------------------
__global__ __launch_bounds__(64) void qlstm_scan4(
    const float* __restrict__ Z,
    const float* __restrict__ Wf, const float* __restrict__ Wi,
    const float* __restrict__ Wu, const float* __restrict__ Wo,
    const float* __restrict__ thf, const float* __restrict__ thi,
    const float* __restrict__ thu, const float* __restrict__ tho,
    float* __restrict__ out, int T, int B, int D)
{
  const int gid = blockIdx.x * 64 + threadIdx.x;
  const int b = gid >> 2, q = gid & 3;
  if (b >= B) return;

  const float* Wg = (q == 0) ? Wf : (q == 1) ? Wi : (q == 2) ? Wu : Wo;
  const float* th = (q == 0) ? thf : (q == 1) ? thi : (q == 2) ? thu : tho;
  const int ldw = D + 4;
  const float ct1 = fast_cos(th[1]);  // cos(theta1) of this lane's gate
  const float m2c = fast_cos(th[2]);  // cos(theta2) of this lane's gate

  // wh[jj][d] pairs with h from lane q^d (component q^d): XOR-permuted load.
  float wh[3][4];
#pragma unroll
  for (int jj = 0; jj < 3; ++jj) {
    int row = (jj == 2) ? 3 : jj;
#pragma unroll
    for (int d = 0; d < 4; ++d)
      wh[jj][d] = Wg[row * ldw + D + (q ^ d)];
  }
  const bool e0 = ((q & 1) == 0);
  const bool e1 = ((q & 2) == 0);

  float h = 0.f, c = 0.f;  // this lane holds component q of h and c

  const float* Zg = Z + gid;
  const size_t tstr = (size_t)12 * B;  // floats per time step
  const size_t pstr = (size_t)4 * B;   // floats per j-plane
  float* hx  = out + (size_t)T * B * 4;
  float* cxp = hx + (size_t)B * 4;

  auto ld3 = [&](int t, float& z0, float& z1, float& z2) {
    const float* p = Zg + (size_t)t * tstr;
    z0 = p[0]; z1 = p[pstr]; z2 = p[2 * pstr];
  };

  auto step = [&](float z0, float z1, float z2, int t) {
    // gather all 4 h components (h from lane q^d)
    float h1 = swzf<SWZ_XOR1>(h);
    float h2 = swzf<SWZ_XOR2>(h);
    float h3 = swzf<SWZ_XOR3>(h);
    float a0 = fmaf(wh[0][0], h, fmaf(wh[0][1], h1, fmaf(wh[0][2], h2, fmaf(wh[0][3], h3, z0))));
    float a1 = fmaf(wh[1][0], h, fmaf(wh[1][1], h1, fmaf(wh[1][2], h2, fmaf(wh[1][3], h3, z1))));
    float a2 = fmaf(wh[2][0], h, fmaf(wh[2][1], h1, fmaf(wh[2][2], h2, fmaf(wh[2][3], h3, z2))));
    // this lane's gate: wire measurements
    float m0 = fast_cos(a0);
    float m1 = ct1 * fast_cos(a1);
    float m3 = fast_cos(a2);
    float m01 = m0 * m1, m23 = m2c * m3;
    float g0 = m1 * m23;        // <Z0> = m1 m2 m3
    float g1 = m01;             // <Z1> = m0 m1
    float g2 = m01 * m2c;       // <Z2> = m0 m1 m2
    float g3 = m01 * m23;       // <Z3> = m0 m1 m2 m3
    // 4x4 quad transpose (two XOR stages); after: w_r = gate r's component q.
    float x0 = swzf<SWZ_XOR1>(g0);
    float x1 = swzf<SWZ_XOR1>(g1);
    float x2 = swzf<SWZ_XOR1>(g2);
    float x3 = swzf<SWZ_XOR1>(g3);
    float s0 = e0 ? g0 : x1;
    float s1 = e0 ? x0 : g1;
    float s2 = e0 ? g2 : x3;
    float s3 = e0 ? x2 : g3;
    float y0 = swzf<SWZ_XOR2>(s0);
    float y1 = swzf<SWZ_XOR2>(s1);
    float y2 = swzf<SWZ_XOR2>(s2);
    float y3 = swzf<SWZ_XOR2>(s3);
    float wf_ = e1 ? s0 : y2;
    float wi_ = e1 ? s1 : y3;
    float wu_ = e1 ? y0 : s2;
    float wo_ = e1 ? y1 : s3;
    // gates (|input| <= 1: products of cosines)
    float fg = sigmoid_poly(wf_);
    float ig = sigmoid_poly(wi_);
    float ug = tanh_pade(wu_);
    float og = sigmoid_poly(wo_);
    c = fmaf(fg, c, ig * ug);
    h = og * tanh_pade(c);
    out[(size_t)t * pstr + gid] = h;
  };

  // depth-4 named prefetch pipeline
  float A0, A1, A2, B0, B1, B2, C0, C1, C2, D0, D1, D2;
  if (T > 0) ld3(0, A0, A1, A2);
  if (T > 1) ld3(1, B0, B1, B2);
  if (T > 2) ld3(2, C0, C1, C2);
  if (T > 3) ld3(3, D0, D1, D2);

  int T4 = T & ~3;
  for (int t = 0; t < T4; t += 4) {
    { float z0 = A0, z1 = A1, z2 = A2;
      if (t + 4 < T) ld3(t + 4, A0, A1, A2);
      step(z0, z1, z2, t); }
    { float z0 = B0, z1 = B1, z2 = B2;
      if (t + 5 < T) ld3(t + 5, B0, B1, B2);
      step(z0, z1, z2, t + 1); }
    { float z0 = C0, z1 = C1, z2 = C2;
      if (t + 6 < T) ld3(t + 6, C0, C1, C2);
      step(z0, z1, z2, t + 2); }
    { float z0 = D0, z1 = D1, z2 = D2;
      if (t + 7 < T) ld3(t + 7, D0, D1, D2);
      step(z0, z1, z2, t + 3); }
  }
  for (int t = T4; t < T; ++t) {
    float z0, z1, z2;
    ld3(t, z0, z1, z2);
    step(z0, z1, z2, t);
  }
  hx[gid]  = h;
  cxp[gid] = c;
}

// ---------------------------------------------------------------------------
// Fallback (only if workspace can't hold Z): fused, slow but correct.
// ---------------------------------------------------------------------------
struct GK {
  float wh[4][3][4];
  float ct1[4];
  float m2c[4];
};

__device__ __forceinline__ void load_gk(GK& K,
    const float* Wf, const float* Wi, const float* Wu, const float* Wo,
    const float* thf, const float* thi, const float* thu, const float* tho,
    int D)
{
  const float* Ws[4] = {Wf, Wi, Wu, Wo};
  const float* ts[4] = {thf, thi, thu, tho};
  const int ldw = D + 4;
#pragma unroll
  for (int g = 0; g < 4; ++g) {
#pragma unroll
    for (int jj = 0; jj < 3; ++jj) {
      int row = (jj == 2) ? 3 : jj;
#pragma unroll
      for (int qq = 0; qq < 4; ++qq)
        K.wh[g][jj][qq] = Ws[g][row * ldw + D + qq];
    }
    K.ct1[g] = fast_cos(ts[g][1]);
    K.m2c[g] = fast_cos(ts[g][2]);
  }
}

__device__ __forceinline__ void qlstm_step_sc(const float a[12], const GK& K,
                                              float h[4], float c[4])
{
  float gv[4][4];
#pragma unroll
  for (int g = 0; g < 4; ++g) {
    float m0 = fast_cos(a[g * 3 + 0]);
    float m1 = K.ct1[g] * fast_cos(a[g * 3 + 1]);
    float m3 = fast_cos(a[g * 3 + 2]);
    float m01 = m0 * m1;
    float m23 = K.m2c[g] * m3;
    gv[g][0] = m1 * m23;
    gv[g][1] = m01;
    gv[g][2] = m01 * K.m2c[g];
    gv[g][3] = m01 * m23;
  }
#pragma unroll
  for (int qq = 0; qq < 4; ++qq) {
    float fg = fast_sigmoid(gv[0][qq]);
    float ig = fast_sigmoid(gv[1][qq]);
    float ug = fast_tanh(gv[2][qq]);
    float og = fast_sigmoid(gv[3][qq]);
    c[qq] = fg * c[qq] + ig * ug;
    h[qq] = og * fast_tanh(c[qq]);
  }
}

__global__ __launch_bounds__(256) void qlstm_fused(
    const float* __restrict__ x,
    const float* __restrict__ Wf, const float* __restrict__ bf,
    const float* __restrict__ Wi, const float* __restrict__ bi,
    const float* __restrict__ Wu, const float* __restrict__ bu,
    const float* __restrict__ Wo, const float* __restrict__ bo,
    const float* __restrict__ thf, const float* __restrict__ thi,
    const float* __restrict__ thu, const float* __restrict__ tho,
    float* __restrict__ out, int T, int B, int D)
{
  int b = blockIdx.x * 256 + threadIdx.x;
  if (b >= B) return;
  GK K;
  load_gk(K, Wf, Wi, Wu, Wo, thf, thi, thu, tho, D);
  const float* Ws[4] = {Wf, Wi, Wu, Wo};
  const float* bs[4] = {bf, bi, bu, bo};
  const float* ts[4] = {thf, thi, thu, tho};
  const int ldw = D + 4;

  float base[12];
#pragma unroll
  for (int g = 0; g < 4; ++g) {
    base[g * 3 + 0] = bs[g][0] + ts[g][0];
    base[g * 3 + 1] = bs[g][1];
    base[g * 3 + 2] = bs[g][3] + ts[g][3];
  }

  float h[4] = {0.f, 0.f, 0.f, 0.f};
  float c[4] = {0.f, 0.f, 0.f, 0.f};
  float* hx  = out + (size_t)T * B * 4;
  float* cxp = hx + (size_t)B * 4;

  for (int t = 0; t < T; ++t) {
    float a[12];
#pragma unroll
    for (int j = 0; j < 12; ++j) a[j] = base[j];
    const float* xp = x + ((size_t)t * B + b) * D;
    for (int k = 0; k < D; k += 4) {
      float4 xv = *(const float4*)(xp + k);
#pragma unroll
      for (int g = 0; g < 4; ++g) {
        const float* W = Ws[g];
#pragma unroll
        for (int jj = 0; jj < 3; ++jj) {
          int row = (jj == 2) ? 3 : jj;
          const float* wp = W + row * ldw + k;
          a[g * 3 + jj] += xv.x * wp[0] + xv.y * wp[1] + xv.z * wp[2] + xv.w * wp[3];
        }
      }
    }
#pragma unroll
    for (int g = 0; g < 4; ++g) {
#pragma unroll
      for (int jj = 0; jj < 3; ++jj) {
        a[g * 3 + jj] += K.wh[g][jj][0] * h[0] + K.wh[g][jj][1] * h[1]
                       + K.wh[g][jj][2] * h[2] + K.wh[g][jj][3] * h[3];
      }
    }
    qlstm_step_sc(a, K, h, c);
    *(float4*)(out + ((size_t)t * B + b) * 4) = make_float4(h[0], h[1], h[2], h[3]);
  }
  *(float4*)(hx + (size_t)b * 4)  = make_float4(h[0], h[1], h[2], h[3]);
  *(float4*)(cxp + (size_t)b * 4) = make_float4(c[0], c[1], c[2], c[3]);
}

// ---------------------------------------------------------------------------
extern "C" void kernel_launch(void* const* d_in, const int* in_sizes, int n_in,
                              void* d_out, int out_size, void* d_ws, size_t ws_size,
                              hipStream_t stream)
{
  const float* x   = (const float*)d_in[0];
  const float* Wf  = (const float*)d_in[1];
  const float* bf  = (const float*)d_in[2];
  const float* Wi  = (const float*)d_in[3];
  const float* bi  = (const float*)d_in[4];
  const float* Wu  = (const float*)d_in[5];
  const float* bu  = (const float*)d_in[6];
  const float* Wo  = (const float*)d_in[7];
  const float* bo  = (const float*)d_in[8];
  const float* thf = (const float*)d_in[9];
  const float* thi = (const float*)d_in[10];
  const float* thu = (const float*)d_in[11];
  const float* tho = (const float*)d_in[12];

  int DH = in_sizes[1] / 4;                 // D + H (H = 4)
  int D  = DH - 4;                          // 128
  long long TB = (long long)in_sizes[0] / D;          // T*B
  int B = (int)(((long long)out_size - 4 * TB) / 8);  // out = 4*T*B + 8*B
  int T = (int)(TB / B);

  size_t zbytes = (size_t)TB * 12 * sizeof(float);
  if (ws_size >= zbytes && (D & 31) == 0) {
    float* Z = (float*)d_ws;
    int gblocks = (int)((TB + 255) / 256);
    qlstm_gemm<<<gblocks, 256, 0, stream>>>(x, Wf, bf, Wi, bi, Wu, bu, Wo, bo,
                                            thf, thi, thu, tho, Z, TB, B, D);
    int sthreads = B * 4;
    qlstm_scan4<<<(sthreads + 63) / 64, 64, 0, stream>>>(Z, Wf, Wi, Wu, Wo,
                                                         thf, thi, thu, tho,
                                                         (float*)d_out, T, B, D);
  } else {
    qlstm_fused<<<(B + 255) / 256, 256, 0, stream>>>(x, Wf, bf, Wi, bi, Wu, bu, Wo, bo,
                                                     thf, thi, thu, tho,
                                                     (float*)d_out, T, B, D);
  }
}

// Round 5
// 78.971 us; speedup vs baseline: 1.5473x; 1.5473x over previous
//
#include <hip/hip_runtime.h>

// ---------------------------------------------------------------------------
// Fast math helpers.
// ---------------------------------------------------------------------------
__device__ __forceinline__ float fast_exp(float x) {
  return __builtin_amdgcn_exp2f(x * 1.4426950408889634f);
}
__device__ __forceinline__ float fast_rcp(float x) {
  return __builtin_amdgcn_rcpf(x);
}
__device__ __forceinline__ float fast_cos(float x) {
  // v_cos takes revolutions; v_fract does the range reduction.
  return __builtin_amdgcn_cosf(__builtin_amdgcn_fractf(x * 0.15915494309189535f));
}
__device__ __forceinline__ float fast_sigmoid(float x) {
  return fast_rcp(1.0f + fast_exp(-x));
}
__device__ __forceinline__ float fast_tanh(float x) {
  return 1.0f - 2.0f * fast_rcp(1.0f + fast_exp(2.0f * x));
}
// sigmoid on [-1,1]: 0.5 + x/4 - x^3/48 + x^5/480 - 17x^7/80640 (err ~2e-5)
__device__ __forceinline__ float sigmoid_poly(float x) {
  float x2 = x * x;
  float p = fmaf(fmaf(fmaf(-2.1085373e-4f, x2, 2.0833334e-3f), x2,
                      -2.0833334e-2f), x2, 0.25f);
  return fmaf(x, p, 0.5f);
}
// tanh Pade(5,4): err <1e-6 @|x|<=1, <1.3e-4 @|x|<=2.5 (cell state bound ~2.1)
__device__ __forceinline__ float tanh_pade(float x) {
  float x2 = x * x;
  float num = x * fmaf(x2 + 105.f, x2, 945.f);
  float den = fmaf(fmaf(15.f, x2, 420.f), x2, 945.f);
  return num * fast_rcp(den);
}

// Cross-lane XOR exchange via ds_swizzle (BitMode: offset=(xor<<10)|0x1F).
// Single DS instruction, all-lane pull semantics: dst[i] = src[i ^ XORM].
template <int PAT>
__device__ __forceinline__ float swzf(float v) {
  return __int_as_float(__builtin_amdgcn_ds_swizzle(__float_as_int(v), PAT));
}
#define SWZ_XOR1 0x041F
#define SWZ_XOR2 0x081F
#define SWZ_XOR3 0x0C1F

// ---------------------------------------------------------------------------
// Kernel 1: precompute x-part of gate activations, LDS-staged for coalescing.
//   Z[t][j][b][g] = x[t,b,:] . W_g[row_j, :D] + fold   (j in {0,1,2} -> linear
// rows {0,1,3}; row 2 is dead: RZ on |0> is a global phase). fold = bias+theta
// for rows 0,3.
// NOTE: loads and LDS stores stay INSIDE the staging loop (no register state
// held across the barrier/compute region) — R4's hoisted pf[8] prefetch was
// spilled to scratch by the allocator: WRITE_SIZE 12.6 MB -> 128 MB, 2.5x dur.
// ---------------------------------------------------------------------------
__global__ __launch_bounds__(256) void qlstm_gemm(
    const float* __restrict__ x,
    const float* __restrict__ Wf, const float* __restrict__ bf,
    const float* __restrict__ Wi, const float* __restrict__ bi,
    const float* __restrict__ Wu, const float* __restrict__ bu,
    const float* __restrict__ Wo, const float* __restrict__ bo,
    const float* __restrict__ thf, const float* __restrict__ thi,
    const float* __restrict__ thu, const float* __restrict__ tho,
    float* __restrict__ Z, long long rows, int B, int D)
{
  __shared__ float tile[256][36];  // LD=36: 2-way bank aliasing only (free)
  const long long base = (long long)blockIdx.x * 256;
  const int tid = threadIdx.x;
  const long long r = base + tid;
  const bool valid = r < rows;
  const int ldw = D + 4;
  const float* Ws[4] = {Wf, Wi, Wu, Wo};
  const float* bs[4] = {bf, bi, bu, bo};
  const float* ts[4] = {thf, thi, thu, tho};

  float acc[12];
#pragma unroll
  for (int g = 0; g < 4; ++g) {
    acc[g * 3 + 0] = bs[g][0] + ts[g][0];  // theta0 folded
    acc[g * 3 + 1] = bs[g][1];
    acc[g * 3 + 2] = bs[g][3] + ts[g][3];  // theta3 folded
  }

  const int nkc = D >> 5;  // D multiple of 32 (D=128)
  for (int kc = 0; kc < nkc; ++kc) {
    // stage 256 rows x 32 cols, coalesced
#pragma unroll
    for (int i = 0; i < 8; ++i) {
      int flat = i * 1024 + tid * 4;
      int row = flat >> 5, col = flat & 31;
      long long gr = base + row;
      if (gr < rows) {
        float4 v = *(const float4*)(x + gr * (long long)D + kc * 32 + col);
        *(float4*)&tile[row][col] = v;
      }
    }
    __syncthreads();
    if (valid) {
#pragma unroll
      for (int k = 0; k < 32; k += 4) {
        float4 xv = *(float4*)&tile[tid][k];
#pragma unroll
        for (int g = 0; g < 4; ++g) {
#pragma unroll
          for (int jj = 0; jj < 3; ++jj) {
            int row2 = (jj == 2) ? 3 : jj;
            const float* wp = Ws[g] + row2 * ldw + kc * 32 + k;  // uniform -> s_load
            acc[g * 3 + jj] += xv.x * wp[0] + xv.y * wp[1] + xv.z * wp[2] + xv.w * wp[3];
          }
        }
      }
    }
    __syncthreads();
  }

  if (valid) {
    long long t = r / B;
    int b = (int)(r - t * B);
    float4 s0 = make_float4(acc[0], acc[3], acc[6], acc[9]);   // a0 per gate
    float4 s1 = make_float4(acc[1], acc[4], acc[7], acc[10]);  // a1 per gate
    float4 s2 = make_float4(acc[2], acc[5], acc[8], acc[11]);  // a3 per gate
    *(float4*)(Z + ((t * 3 + 0) * (long long)B + b) * 4) = s0;
    *(float4*)(Z + ((t * 3 + 1) * (long long)B + b) * 4) = s1;
    *(float4*)(Z + ((t * 3 + 2) * (long long)B + b) * 4) = s2;
  }
}

// ---------------------------------------------------------------------------
// Kernel 2: scan with 4 lanes per batch element (lane q = gate q; after the
// 4x4 quad transpose lane q = component q). Cross-lane via ds_swizzle only.
// ---------------------------------------------------------------------------
__global__ __launch_bounds__(64) void qlstm_scan4(
    const float* __restrict__ Z,
    const float* __restrict__ Wf, const float* __restrict__ Wi,
    const float* __restrict__ Wu, const float* __restrict__ Wo,
    const float* __restrict__ thf, const float* __restrict__ thi,
    const float* __restrict__ thu, const float* __restrict__ tho,
    float* __restrict__ out, int T, int B, int D)
{
  const int gid = blockIdx.x * 64 + threadIdx.x;
  const int b = gid >> 2, q = gid & 3;
  if (b >= B) return;

  const float* Wg = (q == 0) ? Wf : (q == 1) ? Wi : (q == 2) ? Wu : Wo;
  const float* th = (q == 0) ? thf : (q == 1) ? thi : (q == 2) ? thu : tho;
  const int ldw = D + 4;
  const float ct1 = fast_cos(th[1]);  // cos(theta1) of this lane's gate
  const float m2c = fast_cos(th[2]);  // cos(theta2) of this lane's gate

  // wh[jj][d] pairs with h from lane q^d (component q^d): XOR-permuted load.
  float wh[3][4];
#pragma unroll
  for (int jj = 0; jj < 3; ++jj) {
    int row = (jj == 2) ? 3 : jj;
#pragma unroll
    for (int d = 0; d < 4; ++d)
      wh[jj][d] = Wg[row * ldw + D + (q ^ d)];
  }
  const bool e0 = ((q & 1) == 0);
  const bool e1 = ((q & 2) == 0);

  float h = 0.f, c = 0.f;  // this lane holds component q of h and c

  const float* Zg = Z + gid;
  const size_t tstr = (size_t)12 * B;  // floats per time step
  const size_t pstr = (size_t)4 * B;   // floats per j-plane
  float* hx  = out + (size_t)T * B * 4;
  float* cxp = hx + (size_t)B * 4;

  auto ld3 = [&](int t, float& z0, float& z1, float& z2) {
    const float* p = Zg + (size_t)t * tstr;
    z0 = p[0]; z1 = p[pstr]; z2 = p[2 * pstr];
  };

  auto step = [&](float z0, float z1, float z2, int t) {
    // gather all 4 h components (h from lane q^d)
    float h1 = swzf<SWZ_XOR1>(h);
    float h2 = swzf<SWZ_XOR2>(h);
    float h3 = swzf<SWZ_XOR3>(h);
    float a0 = fmaf(wh[0][0], h, fmaf(wh[0][1], h1, fmaf(wh[0][2], h2, fmaf(wh[0][3], h3, z0))));
    float a1 = fmaf(wh[1][0], h, fmaf(wh[1][1], h1, fmaf(wh[1][2], h2, fmaf(wh[1][3], h3, z1))));
    float a2 = fmaf(wh[2][0], h, fmaf(wh[2][1], h1, fmaf(wh[2][2], h2, fmaf(wh[2][3], h3, z2))));
    // this lane's gate: wire measurements
    float m0 = fast_cos(a0);
    float m1 = ct1 * fast_cos(a1);
    float m3 = fast_cos(a2);
    float m01 = m0 * m1, m23 = m2c * m3;
    float g0 = m1 * m23;        // <Z0> = m1 m2 m3
    float g1 = m01;             // <Z1> = m0 m1
    float g2 = m01 * m2c;       // <Z2> = m0 m1 m2
    float g3 = m01 * m23;       // <Z3> = m0 m1 m2 m3
    // 4x4 quad transpose (two XOR stages); after: w_r = gate r's component q.
    float x0 = swzf<SWZ_XOR1>(g0);
    float x1 = swzf<SWZ_XOR1>(g1);
    float x2 = swzf<SWZ_XOR1>(g2);
    float x3 = swzf<SWZ_XOR1>(g3);
    float s0 = e0 ? g0 : x1;
    float s1 = e0 ? x0 : g1;
    float s2 = e0 ? g2 : x3;
    float s3 = e0 ? x2 : g3;
    float y0 = swzf<SWZ_XOR2>(s0);
    float y1 = swzf<SWZ_XOR2>(s1);
    float y2 = swzf<SWZ_XOR2>(s2);
    float y3 = swzf<SWZ_XOR2>(s3);
    float wf_ = e1 ? s0 : y2;
    float wi_ = e1 ? s1 : y3;
    float wu_ = e1 ? y0 : s2;
    float wo_ = e1 ? y1 : s3;
    // gates (|input| <= 1: products of cosines)
    float fg = sigmoid_poly(wf_);
    float ig = sigmoid_poly(wi_);
    float ug = tanh_pade(wu_);
    float og = sigmoid_poly(wo_);
    c = fmaf(fg, c, ig * ug);
    h = og * tanh_pade(c);
    out[(size_t)t * pstr + gid] = h;
  };

  // depth-4 named prefetch pipeline
  float A0, A1, A2, B0, B1, B2, C0, C1, C2, D0, D1, D2;
  if (T > 0) ld3(0, A0, A1, A2);
  if (T > 1) ld3(1, B0, B1, B2);
  if (T > 2) ld3(2, C0, C1, C2);
  if (T > 3) ld3(3, D0, D1, D2);

  int T4 = T & ~3;
  for (int t = 0; t < T4; t += 4) {
    { float z0 = A0, z1 = A1, z2 = A2;
      if (t + 4 < T) ld3(t + 4, A0, A1, A2);
      step(z0, z1, z2, t); }
    { float z0 = B0, z1 = B1, z2 = B2;
      if (t + 5 < T) ld3(t + 5, B0, B1, B2);
      step(z0, z1, z2, t + 1); }
    { float z0 = C0, z1 = C1, z2 = C2;
      if (t + 6 < T) ld3(t + 6, C0, C1, C2);
      step(z0, z1, z2, t + 2); }
    { float z0 = D0, z1 = D1, z2 = D2;
      if (t + 7 < T) ld3(t + 7, D0, D1, D2);
      step(z0, z1, z2, t + 3); }
  }
  for (int t = T4; t < T; ++t) {
    float z0, z1, z2;
    ld3(t, z0, z1, z2);
    step(z0, z1, z2, t);
  }
  hx[gid]  = h;
  cxp[gid] = c;
}

// ---------------------------------------------------------------------------
// Fallback (only if workspace can't hold Z): fused, slow but correct.
// ---------------------------------------------------------------------------
struct GK {
  float wh[4][3][4];
  float ct1[4];
  float m2c[4];
};

__device__ __forceinline__ void load_gk(GK& K,
    const float* Wf, const float* Wi, const float* Wu, const float* Wo,
    const float* thf, const float* thi, const float* thu, const float* tho,
    int D)
{
  const float* Ws[4] = {Wf, Wi, Wu, Wo};
  const float* ts[4] = {thf, thi, thu, tho};
  const int ldw = D + 4;
#pragma unroll
  for (int g = 0; g < 4; ++g) {
#pragma unroll
    for (int jj = 0; jj < 3; ++jj) {
      int row = (jj == 2) ? 3 : jj;
#pragma unroll
      for (int qq = 0; qq < 4; ++qq)
        K.wh[g][jj][qq] = Ws[g][row * ldw + D + qq];
    }
    K.ct1[g] = fast_cos(ts[g][1]);
    K.m2c[g] = fast_cos(ts[g][2]);
  }
}

__device__ __forceinline__ void qlstm_step_sc(const float a[12], const GK& K,
                                              float h[4], float c[4])
{
  float gv[4][4];
#pragma unroll
  for (int g = 0; g < 4; ++g) {
    float m0 = fast_cos(a[g * 3 + 0]);
    float m1 = K.ct1[g] * fast_cos(a[g * 3 + 1]);
    float m3 = fast_cos(a[g * 3 + 2]);
    float m01 = m0 * m1;
    float m23 = K.m2c[g] * m3;
    gv[g][0] = m1 * m23;
    gv[g][1] = m01;
    gv[g][2] = m01 * K.m2c[g];
    gv[g][3] = m01 * m23;
  }
#pragma unroll
  for (int qq = 0; qq < 4; ++qq) {
    float fg = fast_sigmoid(gv[0][qq]);
    float ig = fast_sigmoid(gv[1][qq]);
    float ug = fast_tanh(gv[2][qq]);
    float og = fast_sigmoid(gv[3][qq]);
    c[qq] = fg * c[qq] + ig * ug;
    h[qq] = og * fast_tanh(c[qq]);
  }
}

__global__ __launch_bounds__(256) void qlstm_fused(
    const float* __restrict__ x,
    const float* __restrict__ Wf, const float* __restrict__ bf,
    const float* __restrict__ Wi, const float* __restrict__ bi,
    const float* __restrict__ Wu, const float* __restrict__ bu,
    const float* __restrict__ Wo, const float* __restrict__ bo,
    const float* __restrict__ thf, const float* __restrict__ thi,
    const float* __restrict__ thu, const float* __restrict__ tho,
    float* __restrict__ out, int T, int B, int D)
{
  int b = blockIdx.x * 256 + threadIdx.x;
  if (b >= B) return;
  GK K;
  load_gk(K, Wf, Wi, Wu, Wo, thf, thi, thu, tho, D);
  const float* Ws[4] = {Wf, Wi, Wu, Wo};
  const float* bs[4] = {bf, bi, bu, bo};
  const float* ts[4] = {thf, thi, thu, tho};
  const int ldw = D + 4;

  float base[12];
#pragma unroll
  for (int g = 0; g < 4; ++g) {
    base[g * 3 + 0] = bs[g][0] + ts[g][0];
    base[g * 3 + 1] = bs[g][1];
    base[g * 3 + 2] = bs[g][3] + ts[g][3];
  }

  float h[4] = {0.f, 0.f, 0.f, 0.f};
  float c[4] = {0.f, 0.f, 0.f, 0.f};
  float* hx  = out + (size_t)T * B * 4;
  float* cxp = hx + (size_t)B * 4;

  for (int t = 0; t < T; ++t) {
    float a[12];
#pragma unroll
    for (int j = 0; j < 12; ++j) a[j] = base[j];
    const float* xp = x + ((size_t)t * B + b) * D;
    for (int k = 0; k < D; k += 4) {
      float4 xv = *(const float4*)(xp + k);
#pragma unroll
      for (int g = 0; g < 4; ++g) {
        const float* W = Ws[g];
#pragma unroll
        for (int jj = 0; jj < 3; ++jj) {
          int row = (jj == 2) ? 3 : jj;
          const float* wp = W + row * ldw + k;
          a[g * 3 + jj] += xv.x * wp[0] + xv.y * wp[1] + xv.z * wp[2] + xv.w * wp[3];
        }
      }
    }
#pragma unroll
    for (int g = 0; g < 4; ++g) {
#pragma unroll
      for (int jj = 0; jj < 3; ++jj) {
        a[g * 3 + jj] += K.wh[g][jj][0] * h[0] + K.wh[g][jj][1] * h[1]
                       + K.wh[g][jj][2] * h[2] + K.wh[g][jj][3] * h[3];
      }
    }
    qlstm_step_sc(a, K, h, c);
    *(float4*)(out + ((size_t)t * B + b) * 4) = make_float4(h[0], h[1], h[2], h[3]);
  }
  *(float4*)(hx + (size_t)b * 4)  = make_float4(h[0], h[1], h[2], h[3]);
  *(float4*)(cxp + (size_t)b * 4) = make_float4(c[0], c[1], c[2], c[3]);
}

// ---------------------------------------------------------------------------
extern "C" void kernel_launch(void* const* d_in, const int* in_sizes, int n_in,
                              void* d_out, int out_size, void* d_ws, size_t ws_size,
                              hipStream_t stream)
{
  const float* x   = (const float*)d_in[0];
  const float* Wf  = (const float*)d_in[1];
  const float* bf  = (const float*)d_in[2];
  const float* Wi  = (const float*)d_in[3];
  const float* bi  = (const float*)d_in[4];
  const float* Wu  = (const float*)d_in[5];
  const float* bu  = (const float*)d_in[6];
  const float* Wo  = (const float*)d_in[7];
  const float* bo  = (const float*)d_in[8];
  const float* thf = (const float*)d_in[9];
  const float* thi = (const float*)d_in[10];
  const float* thu = (const float*)d_in[11];
  const float* tho = (const float*)d_in[12];

  int DH = in_sizes[1] / 4;                 // D + H (H = 4)
  int D  = DH - 4;                          // 128
  long long TB = (long long)in_sizes[0] / D;          // T*B
  int B = (int)(((long long)out_size - 4 * TB) / 8);  // out = 4*T*B + 8*B
  int T = (int)(TB / B);

  size_t zbytes = (size_t)TB * 12 * sizeof(float);
  if (ws_size >= zbytes && (D & 31) == 0) {
    float* Z = (float*)d_ws;
    int gblocks = (int)((TB + 255) / 256);
    qlstm_gemm<<<gblocks, 256, 0, stream>>>(x, Wf, bf, Wi, bi, Wu, bu, Wo, bo,
                                            thf, thi, thu, tho, Z, TB, B, D);
    int sthreads = B * 4;
    qlstm_scan4<<<(sthreads + 63) / 64, 64, 0, stream>>>(Z, Wf, Wi, Wu, Wo,
                                                         thf, thi, thu, tho,
                                                         (float*)d_out, T, B, D);
  } else {
    qlstm_fused<<<(B + 255) / 256, 256, 0, stream>>>(x, Wf, bf, Wi, bi, Wu, bu, Wo, bo,
                                                     thf, thi, thu, tho,
                                                     (float*)d_out, T, B, D);
  }
}

// Round 6
// 77.176 us; speedup vs baseline: 1.5833x; 1.0232x over previous
//
#include <hip/hip_runtime.h>

// ---------------------------------------------------------------------------
// Fast math helpers.
// ---------------------------------------------------------------------------
__device__ __forceinline__ float fast_exp(float x) {
  return __builtin_amdgcn_exp2f(x * 1.4426950408889634f);
}
__device__ __forceinline__ float fast_rcp(float x) {
  return __builtin_amdgcn_rcpf(x);
}
__device__ __forceinline__ float fast_cos(float x) {
  // v_cos takes revolutions; v_fract does the range reduction.
  return __builtin_amdgcn_cosf(__builtin_amdgcn_fractf(x * 0.15915494309189535f));
}
__device__ __forceinline__ float fast_sigmoid(float x) {
  return fast_rcp(1.0f + fast_exp(-x));
}
__device__ __forceinline__ float fast_tanh(float x) {
  return 1.0f - 2.0f * fast_rcp(1.0f + fast_exp(2.0f * x));
}
// sigmoid on [-1,1]: 0.5 + x/4 - x^3/48 + x^5/480 - 17x^7/80640 (err ~2e-5)
__device__ __forceinline__ float sigmoid_poly(float x) {
  float x2 = x * x;
  float p = fmaf(fmaf(fmaf(-2.1085373e-4f, x2, 2.0833334e-3f), x2,
                      -2.0833334e-2f), x2, 0.25f);
  return fmaf(x, p, 0.5f);
}
// tanh Pade(5,4): err <1e-6 @|x|<=1, <1.3e-4 @|x|<=2.5 (cell state bound ~2.1)
__device__ __forceinline__ float tanh_pade(float x) {
  float x2 = x * x;
  float num = x * fmaf(x2 + 105.f, x2, 945.f);
  float den = fmaf(fmaf(15.f, x2, 420.f), x2, 945.f);
  return num * fast_rcp(den);
}

// Cross-lane XOR exchange via ds_swizzle (BitMode: offset=(xor<<10)|0x1F).
// Single DS instruction, all-lane pull semantics: dst[i] = src[i ^ XORM].
template <int PAT>
__device__ __forceinline__ float swzf(float v) {
  return __int_as_float(__builtin_amdgcn_ds_swizzle(__float_as_int(v), PAT));
}
#define SWZ_XOR1 0x041F
#define SWZ_XOR2 0x081F
#define SWZ_XOR3 0x0C1F

// ---------------------------------------------------------------------------
// Kernel 1: precompute x-part of gate activations.
//   Z[t][j][b][g] = x[t,b,:] . W_g[row_j, :D] + fold   (j in {0,1,2} -> linear
// rows {0,1,3}; row 2 is dead: RZ on |0> is a global phase). fold = bias+theta
// for rows 0,3.
// Structure notes (evidence-driven):
//  - 1-WAVE workgroups (64 threads, 9 KB LDS -> ~17 blocks/CU). R2/R5's
//    256-thread blocks barrier-locked 4 waves into lockstep load/compute
//    phases -> ~50% memory duty (~3 TB/s). Independent waves desync and
//    overlap naturally.
//  - loads feed ds_write immediately (no register state across barriers):
//    R4's hoisted prefetch was spilled to scratch (WRITE_SIZE 12.6->128 MB).
//  - stride 36 floats: measured 0 bank conflicts (R2/R5).
// ---------------------------------------------------------------------------
__global__ __launch_bounds__(64) void qlstm_gemm(
    const float* __restrict__ x,
    const float* __restrict__ Wf, const float* __restrict__ bf,
    const float* __restrict__ Wi, const float* __restrict__ bi,
    const float* __restrict__ Wu, const float* __restrict__ bu,
    const float* __restrict__ Wo, const float* __restrict__ bo,
    const float* __restrict__ thf, const float* __restrict__ thi,
    const float* __restrict__ thu, const float* __restrict__ tho,
    float* __restrict__ Z, long long rows, int B, int D)
{
  __shared__ float tile[64][36];
  const long long base = (long long)blockIdx.x * 64;
  const int tid = threadIdx.x;  // 0..63
  const long long r = base + tid;
  const bool valid = r < rows;
  const int ldw = D + 4;
  const float* Ws[4] = {Wf, Wi, Wu, Wo};
  const float* bs[4] = {bf, bi, bu, bo};
  const float* ts[4] = {thf, thi, thu, tho};

  float acc[12];
#pragma unroll
  for (int g = 0; g < 4; ++g) {
    acc[g * 3 + 0] = bs[g][0] + ts[g][0];  // theta0 folded
    acc[g * 3 + 1] = bs[g][1];
    acc[g * 3 + 2] = bs[g][3] + ts[g][3];  // theta3 folded
  }

  const int nkc = D >> 5;  // D multiple of 32 (D=128)
  for (int kc = 0; kc < nkc; ++kc) {
    // stage 64 rows x 32 cols, coalesced (8 rows of 128B per instruction)
#pragma unroll
    for (int i = 0; i < 8; ++i) {
      int f = i * 64 + tid;
      int row = f >> 3, col = (f & 7) * 4;
      long long gr = base + row;
      if (gr < rows) {
        float4 v = *(const float4*)(x + gr * (long long)D + kc * 32 + col);
        *(float4*)&tile[row][col] = v;
      }
    }
    __syncthreads();  // 1-wave workgroup: near-free
    if (valid) {
#pragma unroll
      for (int k = 0; k < 32; k += 4) {
        float4 xv = *(float4*)&tile[tid][k];
#pragma unroll
        for (int g = 0; g < 4; ++g) {
#pragma unroll
          for (int jj = 0; jj < 3; ++jj) {
            int row2 = (jj == 2) ? 3 : jj;
            const float* wp = Ws[g] + row2 * ldw + kc * 32 + k;  // uniform -> s_load
            acc[g * 3 + jj] += xv.x * wp[0] + xv.y * wp[1] + xv.z * wp[2] + xv.w * wp[3];
          }
        }
      }
    }
    __syncthreads();
  }

  if (valid) {
    long long t = r / B;
    int b = (int)(r - t * B);
    float4 s0 = make_float4(acc[0], acc[3], acc[6], acc[9]);   // a0 per gate
    float4 s1 = make_float4(acc[1], acc[4], acc[7], acc[10]);  // a1 per gate
    float4 s2 = make_float4(acc[2], acc[5], acc[8], acc[11]);  // a3 per gate
    *(float4*)(Z + ((t * 3 + 0) * (long long)B + b) * 4) = s0;
    *(float4*)(Z + ((t * 3 + 1) * (long long)B + b) * 4) = s1;
    *(float4*)(Z + ((t * 3 + 2) * (long long)B + b) * 4) = s2;
  }
}

// ---------------------------------------------------------------------------
// Kernel 2: scan with 4 lanes per batch element (lane q = gate q; after the
// 4x4 quad transpose lane q = component q). Cross-lane via ds_swizzle only.
// ---------------------------------------------------------------------------
__global__ __launch_bounds__(64) void qlstm_scan4(
    const float* __restrict__ Z,
    const float* __restrict__ Wf, const float* __restrict__ Wi,
    const float* __restrict__ Wu, const float* __restrict__ Wo,
    const float* __restrict__ thf, const float* __restrict__ thi,
    const float* __restrict__ thu, const float* __restrict__ tho,
    float* __restrict__ out, int T, int B, int D)
{
  const int gid = blockIdx.x * 64 + threadIdx.x;
  const int b = gid >> 2, q = gid & 3;
  if (b >= B) return;

  const float* Wg = (q == 0) ? Wf : (q == 1) ? Wi : (q == 2) ? Wu : Wo;
  const float* th = (q == 0) ? thf : (q == 1) ? thi : (q == 2) ? thu : tho;
  const int ldw = D + 4;
  const float ct1 = fast_cos(th[1]);  // cos(theta1) of this lane's gate
  const float m2c = fast_cos(th[2]);  // cos(theta2) of this lane's gate

  // wh[jj][d] pairs with h from lane q^d (component q^d): XOR-permuted load.
  float wh[3][4];
#pragma unroll
  for (int jj = 0; jj < 3; ++jj) {
    int row = (jj == 2) ? 3 : jj;
#pragma unroll
    for (int d = 0; d < 4; ++d)
      wh[jj][d] = Wg[row * ldw + D + (q ^ d)];
  }
  const bool e0 = ((q & 1) == 0);
  const bool e1 = ((q & 2) == 0);

  float h = 0.f, c = 0.f;  // this lane holds component q of h and c

  const float* Zg = Z + gid;
  const size_t tstr = (size_t)12 * B;  // floats per time step
  const size_t pstr = (size_t)4 * B;   // floats per j-plane
  float* hx  = out + (size_t)T * B * 4;
  float* cxp = hx + (size_t)B * 4;

  auto ld3 = [&](int t, float& z0, float& z1, float& z2) {
    const float* p = Zg + (size_t)t * tstr;
    z0 = p[0]; z1 = p[pstr]; z2 = p[2 * pstr];
  };

  auto step = [&](float z0, float z1, float z2, int t) {
    // gather all 4 h components (h from lane q^d)
    float h1 = swzf<SWZ_XOR1>(h);
    float h2 = swzf<SWZ_XOR2>(h);
    float h3 = swzf<SWZ_XOR3>(h);
    float a0 = fmaf(wh[0][0], h, fmaf(wh[0][1], h1, fmaf(wh[0][2], h2, fmaf(wh[0][3], h3, z0))));
    float a1 = fmaf(wh[1][0], h, fmaf(wh[1][1], h1, fmaf(wh[1][2], h2, fmaf(wh[1][3], h3, z1))));
    float a2 = fmaf(wh[2][0], h, fmaf(wh[2][1], h1, fmaf(wh[2][2], h2, fmaf(wh[2][3], h3, z2))));
    // this lane's gate: wire measurements
    float m0 = fast_cos(a0);
    float m1 = ct1 * fast_cos(a1);
    float m3 = fast_cos(a2);
    float m01 = m0 * m1, m23 = m2c * m3;
    float g0 = m1 * m23;        // <Z0> = m1 m2 m3
    float g1 = m01;             // <Z1> = m0 m1
    float g2 = m01 * m2c;       // <Z2> = m0 m1 m2
    float g3 = m01 * m23;       // <Z3> = m0 m1 m2 m3
    // 4x4 quad transpose (two XOR stages); after: w_r = gate r's component q.
    float x0 = swzf<SWZ_XOR1>(g0);
    float x1 = swzf<SWZ_XOR1>(g1);
    float x2 = swzf<SWZ_XOR1>(g2);
    float x3 = swzf<SWZ_XOR1>(g3);
    float s0 = e0 ? g0 : x1;
    float s1 = e0 ? x0 : g1;
    float s2 = e0 ? g2 : x3;
    float s3 = e0 ? x2 : g3;
    float y0 = swzf<SWZ_XOR2>(s0);
    float y1 = swzf<SWZ_XOR2>(s1);
    float y2 = swzf<SWZ_XOR2>(s2);
    float y3 = swzf<SWZ_XOR2>(s3);
    float wf_ = e1 ? s0 : y2;
    float wi_ = e1 ? s1 : y3;
    float wu_ = e1 ? y0 : s2;
    float wo_ = e1 ? y1 : s3;
    // gates (|input| <= 1: products of cosines)
    float fg = sigmoid_poly(wf_);
    float ig = sigmoid_poly(wi_);
    float ug = tanh_pade(wu_);
    float og = sigmoid_poly(wo_);
    c = fmaf(fg, c, ig * ug);
    h = og * tanh_pade(c);
    out[(size_t)t * pstr + gid] = h;
  };

  // depth-4 named prefetch pipeline
  float A0, A1, A2, B0, B1, B2, C0, C1, C2, D0, D1, D2;
  if (T > 0) ld3(0, A0, A1, A2);
  if (T > 1) ld3(1, B0, B1, B2);
  if (T > 2) ld3(2, C0, C1, C2);
  if (T > 3) ld3(3, D0, D1, D2);

  int T4 = T & ~3;
  for (int t = 0; t < T4; t += 4) {
    { float z0 = A0, z1 = A1, z2 = A2;
      if (t + 4 < T) ld3(t + 4, A0, A1, A2);
      step(z0, z1, z2, t); }
    { float z0 = B0, z1 = B1, z2 = B2;
      if (t + 5 < T) ld3(t + 5, B0, B1, B2);
      step(z0, z1, z2, t + 1); }
    { float z0 = C0, z1 = C1, z2 = C2;
      if (t + 6 < T) ld3(t + 6, C0, C1, C2);
      step(z0, z1, z2, t + 2); }
    { float z0 = D0, z1 = D1, z2 = D2;
      if (t + 7 < T) ld3(t + 7, D0, D1, D2);
      step(z0, z1, z2, t + 3); }
  }
  for (int t = T4; t < T; ++t) {
    float z0, z1, z2;
    ld3(t, z0, z1, z2);
    step(z0, z1, z2, t);
  }
  hx[gid]  = h;
  cxp[gid] = c;
}

// ---------------------------------------------------------------------------
// Fallback (only if workspace can't hold Z): fused, slow but correct.
// ---------------------------------------------------------------------------
struct GK {
  float wh[4][3][4];
  float ct1[4];
  float m2c[4];
};

__device__ __forceinline__ void load_gk(GK& K,
    const float* Wf, const float* Wi, const float* Wu, const float* Wo,
    const float* thf, const float* thi, const float* thu, const float* tho,
    int D)
{
  const float* Ws[4] = {Wf, Wi, Wu, Wo};
  const float* ts[4] = {thf, thi, thu, tho};
  const int ldw = D + 4;
#pragma unroll
  for (int g = 0; g < 4; ++g) {
#pragma unroll
    for (int jj = 0; jj < 3; ++jj) {
      int row = (jj == 2) ? 3 : jj;
#pragma unroll
      for (int qq = 0; qq < 4; ++qq)
        K.wh[g][jj][qq] = Ws[g][row * ldw + D + qq];
    }
    K.ct1[g] = fast_cos(ts[g][1]);
    K.m2c[g] = fast_cos(ts[g][2]);
  }
}

__device__ __forceinline__ void qlstm_step_sc(const float a[12], const GK& K,
                                              float h[4], float c[4])
{
  float gv[4][4];
#pragma unroll
  for (int g = 0; g < 4; ++g) {
    float m0 = fast_cos(a[g * 3 + 0]);
    float m1 = K.ct1[g] * fast_cos(a[g * 3 + 1]);
    float m3 = fast_cos(a[g * 3 + 2]);
    float m01 = m0 * m1;
    float m23 = K.m2c[g] * m3;
    gv[g][0] = m1 * m23;
    gv[g][1] = m01;
    gv[g][2] = m01 * K.m2c[g];
    gv[g][3] = m01 * m23;
  }
#pragma unroll
  for (int qq = 0; qq < 4; ++qq) {
    float fg = fast_sigmoid(gv[0][qq]);
    float ig = fast_sigmoid(gv[1][qq]);
    float ug = fast_tanh(gv[2][qq]);
    float og = fast_sigmoid(gv[3][qq]);
    c[qq] = fg * c[qq] + ig * ug;
    h[qq] = og * fast_tanh(c[qq]);
  }
}

__global__ __launch_bounds__(256) void qlstm_fused(
    const float* __restrict__ x,
    const float* __restrict__ Wf, const float* __restrict__ bf,
    const float* __restrict__ Wi, const float* __restrict__ bi,
    const float* __restrict__ Wu, const float* __restrict__ bu,
    const float* __restrict__ Wo, const float* __restrict__ bo,
    const float* __restrict__ thf, const float* __restrict__ thi,
    const float* __restrict__ thu, const float* __restrict__ tho,
    float* __restrict__ out, int T, int B, int D)
{
  int b = blockIdx.x * 256 + threadIdx.x;
  if (b >= B) return;
  GK K;
  load_gk(K, Wf, Wi, Wu, Wo, thf, thi, thu, tho, D);
  const float* Ws[4] = {Wf, Wi, Wu, Wo};
  const float* bs[4] = {bf, bi, bu, bo};
  const float* ts[4] = {thf, thi, thu, tho};
  const int ldw = D + 4;

  float base[12];
#pragma unroll
  for (int g = 0; g < 4; ++g) {
    base[g * 3 + 0] = bs[g][0] + ts[g][0];
    base[g * 3 + 1] = bs[g][1];
    base[g * 3 + 2] = bs[g][3] + ts[g][3];
  }

  float h[4] = {0.f, 0.f, 0.f, 0.f};
  float c[4] = {0.f, 0.f, 0.f, 0.f};
  float* hx  = out + (size_t)T * B * 4;
  float* cxp = hx + (size_t)B * 4;

  for (int t = 0; t < T; ++t) {
    float a[12];
#pragma unroll
    for (int j = 0; j < 12; ++j) a[j] = base[j];
    const float* xp = x + ((size_t)t * B + b) * D;
    for (int k = 0; k < D; k += 4) {
      float4 xv = *(const float4*)(xp + k);
#pragma unroll
      for (int g = 0; g < 4; ++g) {
        const float* W = Ws[g];
#pragma unroll
        for (int jj = 0; jj < 3; ++jj) {
          int row = (jj == 2) ? 3 : jj;
          const float* wp = W + row * ldw + k;
          a[g * 3 + jj] += xv.x * wp[0] + xv.y * wp[1] + xv.z * wp[2] + xv.w * wp[3];
        }
      }
    }
#pragma unroll
    for (int g = 0; g < 4; ++g) {
#pragma unroll
      for (int jj = 0; jj < 3; ++jj) {
        a[g * 3 + jj] += K.wh[g][jj][0] * h[0] + K.wh[g][jj][1] * h[1]
                       + K.wh[g][jj][2] * h[2] + K.wh[g][jj][3] * h[3];
      }
    }
    qlstm_step_sc(a, K, h, c);
    *(float4*)(out + ((size_t)t * B + b) * 4) = make_float4(h[0], h[1], h[2], h[3]);
  }
  *(float4*)(hx + (size_t)b * 4)  = make_float4(h[0], h[1], h[2], h[3]);
  *(float4*)(cxp + (size_t)b * 4) = make_float4(c[0], c[1], c[2], c[3]);
}

// ---------------------------------------------------------------------------
extern "C" void kernel_launch(void* const* d_in, const int* in_sizes, int n_in,
                              void* d_out, int out_size, void* d_ws, size_t ws_size,
                              hipStream_t stream)
{
  const float* x   = (const float*)d_in[0];
  const float* Wf  = (const float*)d_in[1];
  const float* bf  = (const float*)d_in[2];
  const float* Wi  = (const float*)d_in[3];
  const float* bi  = (const float*)d_in[4];
  const float* Wu  = (const float*)d_in[5];
  const float* bu  = (const float*)d_in[6];
  const float* Wo  = (const float*)d_in[7];
  const float* bo  = (const float*)d_in[8];
  const float* thf = (const float*)d_in[9];
  const float* thi = (const float*)d_in[10];
  const float* thu = (const float*)d_in[11];
  const float* tho = (const float*)d_in[12];

  int DH = in_sizes[1] / 4;                 // D + H (H = 4)
  int D  = DH - 4;                          // 128
  long long TB = (long long)in_sizes[0] / D;          // T*B
  int B = (int)(((long long)out_size - 4 * TB) / 8);  // out = 4*T*B + 8*B
  int T = (int)(TB / B);

  size_t zbytes = (size_t)TB * 12 * sizeof(float);
  if (ws_size >= zbytes && (D & 31) == 0) {
    float* Z = (float*)d_ws;
    int gblocks = (int)((TB + 63) / 64);
    qlstm_gemm<<<gblocks, 64, 0, stream>>>(x, Wf, bf, Wi, bi, Wu, bu, Wo, bo,
                                           thf, thi, thu, tho, Z, TB, B, D);
    int sthreads = B * 4;
    qlstm_scan4<<<(sthreads + 63) / 64, 64, 0, stream>>>(Z, Wf, Wi, Wu, Wo,
                                                         thf, thi, thu, tho,
                                                         (float*)d_out, T, B, D);
  } else {
    qlstm_fused<<<(B + 255) / 256, 256, 0, stream>>>(x, Wf, bf, Wi, bi, Wu, bu, Wo, bo,
                                                     thf, thi, thu, tho,
                                                     (float*)d_out, T, B, D);
  }
}

// Round 7
// 69.538 us; speedup vs baseline: 1.7572x; 1.1098x over previous
//
#include <hip/hip_runtime.h>

// ---------------------------------------------------------------------------
// Fast math helpers.
// ---------------------------------------------------------------------------
__device__ __forceinline__ float fast_exp(float x) {
  return __builtin_amdgcn_exp2f(x * 1.4426950408889634f);
}
__device__ __forceinline__ float fast_rcp(float x) {
  return __builtin_amdgcn_rcpf(x);
}
__device__ __forceinline__ float fast_cos(float x) {
  // v_cos takes revolutions; v_fract does the range reduction.
  return __builtin_amdgcn_cosf(__builtin_amdgcn_fractf(x * 0.15915494309189535f));
}
__device__ __forceinline__ float fast_sigmoid(float x) {
  return fast_rcp(1.0f + fast_exp(-x));
}
__device__ __forceinline__ float fast_tanh(float x) {
  return 1.0f - 2.0f * fast_rcp(1.0f + fast_exp(2.0f * x));
}
// sigmoid on [-1,1]: 0.5 + x/4 - x^3/48 + x^5/480 - 17x^7/80640 (err ~2e-5)
__device__ __forceinline__ float sigmoid_poly(float x) {
  float x2 = x * x;
  float p = fmaf(fmaf(fmaf(-2.1085373e-4f, x2, 2.0833334e-3f), x2,
                      -2.0833334e-2f), x2, 0.25f);
  return fmaf(x, p, 0.5f);
}
// tanh Pade(5,4): err <1e-6 @|x|<=1, <1.3e-4 @|x|<=2.5 (cell state bound ~2.1)
__device__ __forceinline__ float tanh_pade(float x) {
  float x2 = x * x;
  float num = x * fmaf(x2 + 105.f, x2, 945.f);
  float den = fmaf(fmaf(15.f, x2, 420.f), x2, 945.f);
  return num * fast_rcp(den);
}

// Cross-lane XOR exchange within each 4-lane quad via DPP quad_perm.
// update_dpp (tied old operand, rocPRIM-production path) — NOT the legacy
// mov_dpp builtin that miscompiled in R3. Pure VALU (~2-4 cy), replaces
// ds_swizzle's ~120 cy DS-pipe latency which dominated the scan chain (R6).
// quad_perm ctrl: [a,b,c,d] -> ctrl = a | b<<2 | c<<4 | d<<6
template <int CTRL>
__device__ __forceinline__ float dppf(float v) {
  return __int_as_float(__builtin_amdgcn_update_dpp(
      0, __float_as_int(v), CTRL, 0xf, 0xf, true));
}
#define QP_XOR1 0xB1  // [1,0,3,2]
#define QP_XOR2 0x4E  // [2,3,0,1]
#define QP_XOR3 0x1B  // [3,2,1,0]

// ---------------------------------------------------------------------------
// Kernel 1: precompute x-part of gate activations.
//   Z[t][j][b][g] = x[t,b,:] . W_g[row_j, :D] + fold   (j in {0,1,2} -> linear
// rows {0,1,3}; row 2 is dead: RZ on |0> is a global phase). fold = bias+theta
// for rows 0,3.
// Structure notes (evidence-driven):
//  - 1-wave workgroups; in the timed graph x is L3-resident (134 MB < 256 MB)
//    and gemm runs ~35 us; rocprof replays are cold (fills evict L3).
//  - loads feed ds_write immediately (no register state across barriers):
//    R4's hoisted prefetch was spilled to scratch (WRITE_SIZE 12.6->128 MB).
//  - stride 36 floats: measured 0 bank conflicts (R2/R5).
// ---------------------------------------------------------------------------
__global__ __launch_bounds__(64) void qlstm_gemm(
    const float* __restrict__ x,
    const float* __restrict__ Wf, const float* __restrict__ bf,
    const float* __restrict__ Wi, const float* __restrict__ bi,
    const float* __restrict__ Wu, const float* __restrict__ bu,
    const float* __restrict__ Wo, const float* __restrict__ bo,
    const float* __restrict__ thf, const float* __restrict__ thi,
    const float* __restrict__ thu, const float* __restrict__ tho,
    float* __restrict__ Z, long long rows, int B, int D)
{
  __shared__ float tile[64][36];
  const long long base = (long long)blockIdx.x * 64;
  const int tid = threadIdx.x;  // 0..63
  const long long r = base + tid;
  const bool valid = r < rows;
  const int ldw = D + 4;
  const float* Ws[4] = {Wf, Wi, Wu, Wo};
  const float* bs[4] = {bf, bi, bu, bo};
  const float* ts[4] = {thf, thi, thu, tho};

  float acc[12];
#pragma unroll
  for (int g = 0; g < 4; ++g) {
    acc[g * 3 + 0] = bs[g][0] + ts[g][0];  // theta0 folded
    acc[g * 3 + 1] = bs[g][1];
    acc[g * 3 + 2] = bs[g][3] + ts[g][3];  // theta3 folded
  }

  const int nkc = D >> 5;  // D multiple of 32 (D=128)
  for (int kc = 0; kc < nkc; ++kc) {
    // stage 64 rows x 32 cols, coalesced (8 rows of 128B per instruction)
#pragma unroll
    for (int i = 0; i < 8; ++i) {
      int f = i * 64 + tid;
      int row = f >> 3, col = (f & 7) * 4;
      long long gr = base + row;
      if (gr < rows) {
        float4 v = *(const float4*)(x + gr * (long long)D + kc * 32 + col);
        *(float4*)&tile[row][col] = v;
      }
    }
    __syncthreads();  // 1-wave workgroup: near-free
    if (valid) {
#pragma unroll
      for (int k = 0; k < 32; k += 4) {
        float4 xv = *(float4*)&tile[tid][k];
#pragma unroll
        for (int g = 0; g < 4; ++g) {
#pragma unroll
          for (int jj = 0; jj < 3; ++jj) {
            int row2 = (jj == 2) ? 3 : jj;
            const float* wp = Ws[g] + row2 * ldw + kc * 32 + k;  // uniform -> s_load
            acc[g * 3 + jj] += xv.x * wp[0] + xv.y * wp[1] + xv.z * wp[2] + xv.w * wp[3];
          }
        }
      }
    }
    __syncthreads();
  }

  if (valid) {
    long long t = r / B;
    int b = (int)(r - t * B);
    float4 s0 = make_float4(acc[0], acc[3], acc[6], acc[9]);   // a0 per gate
    float4 s1 = make_float4(acc[1], acc[4], acc[7], acc[10]);  // a1 per gate
    float4 s2 = make_float4(acc[2], acc[5], acc[8], acc[11]);  // a3 per gate
    *(float4*)(Z + ((t * 3 + 0) * (long long)B + b) * 4) = s0;
    *(float4*)(Z + ((t * 3 + 1) * (long long)B + b) * 4) = s1;
    *(float4*)(Z + ((t * 3 + 2) * (long long)B + b) * 4) = s2;
  }
}

// ---------------------------------------------------------------------------
// Kernel 2: scan with 4 lanes per batch element (lane q = gate q; after the
// 4x4 quad transpose lane q = component q). Cross-lane via DPP quad_perm.
// Structure identical to the ds_swizzle version verified in R4-R6; only the
// cross-lane instrument changed (DS pipe ~120cy -> VALU ~4cy).
// ---------------------------------------------------------------------------
__global__ __launch_bounds__(64) void qlstm_scan4(
    const float* __restrict__ Z,
    const float* __restrict__ Wf, const float* __restrict__ Wi,
    const float* __restrict__ Wu, const float* __restrict__ Wo,
    const float* __restrict__ thf, const float* __restrict__ thi,
    const float* __restrict__ thu, const float* __restrict__ tho,
    float* __restrict__ out, int T, int B, int D)
{
  const int gid = blockIdx.x * 64 + threadIdx.x;
  const int b = gid >> 2, q = gid & 3;
  if (b >= B) return;

  const float* Wg = (q == 0) ? Wf : (q == 1) ? Wi : (q == 2) ? Wu : Wo;
  const float* th = (q == 0) ? thf : (q == 1) ? thi : (q == 2) ? thu : tho;
  const int ldw = D + 4;
  const float ct1 = fast_cos(th[1]);  // cos(theta1) of this lane's gate
  const float m2c = fast_cos(th[2]);  // cos(theta2) of this lane's gate

  // wh[jj][d] pairs with h from lane q^d (component q^d): XOR-permuted load.
  float wh[3][4];
#pragma unroll
  for (int jj = 0; jj < 3; ++jj) {
    int row = (jj == 2) ? 3 : jj;
#pragma unroll
    for (int d = 0; d < 4; ++d)
      wh[jj][d] = Wg[row * ldw + D + (q ^ d)];
  }
  const bool e0 = ((q & 1) == 0);
  const bool e1 = ((q & 2) == 0);

  float h = 0.f, c = 0.f;  // this lane holds component q of h and c

  const float* Zg = Z + gid;
  const size_t tstr = (size_t)12 * B;  // floats per time step
  const size_t pstr = (size_t)4 * B;   // floats per j-plane
  float* hx  = out + (size_t)T * B * 4;
  float* cxp = hx + (size_t)B * 4;

  auto ld3 = [&](int t, float& z0, float& z1, float& z2) {
    const float* p = Zg + (size_t)t * tstr;
    z0 = p[0]; z1 = p[pstr]; z2 = p[2 * pstr];
  };

  auto step = [&](float z0, float z1, float z2, int t) {
    // gather all 4 h components (h from lane q^d)
    float h1 = dppf<QP_XOR1>(h);
    float h2 = dppf<QP_XOR2>(h);
    float h3 = dppf<QP_XOR3>(h);
    float a0 = fmaf(wh[0][0], h, fmaf(wh[0][1], h1, fmaf(wh[0][2], h2, fmaf(wh[0][3], h3, z0))));
    float a1 = fmaf(wh[1][0], h, fmaf(wh[1][1], h1, fmaf(wh[1][2], h2, fmaf(wh[1][3], h3, z1))));
    float a2 = fmaf(wh[2][0], h, fmaf(wh[2][1], h1, fmaf(wh[2][2], h2, fmaf(wh[2][3], h3, z2))));
    // this lane's gate: wire measurements
    float m0 = fast_cos(a0);
    float m1 = ct1 * fast_cos(a1);
    float m3 = fast_cos(a2);
    float m01 = m0 * m1, m23 = m2c * m3;
    float g0 = m1 * m23;        // <Z0> = m1 m2 m3
    float g1 = m01;             // <Z1> = m0 m1
    float g2 = m01 * m2c;       // <Z2> = m0 m1 m2
    float g3 = m01 * m23;       // <Z3> = m0 m1 m2 m3
    // 4x4 quad transpose (two XOR stages); after: w_r = gate r's component q.
    float x0 = dppf<QP_XOR1>(g0);
    float x1 = dppf<QP_XOR1>(g1);
    float x2 = dppf<QP_XOR1>(g2);
    float x3 = dppf<QP_XOR1>(g3);
    float s0 = e0 ? g0 : x1;
    float s1 = e0 ? x0 : g1;
    float s2 = e0 ? g2 : x3;
    float s3 = e0 ? x2 : g3;
    float y0 = dppf<QP_XOR2>(s0);
    float y1 = dppf<QP_XOR2>(s1);
    float y2 = dppf<QP_XOR2>(s2);
    float y3 = dppf<QP_XOR2>(s3);
    float wf_ = e1 ? s0 : y2;
    float wi_ = e1 ? s1 : y3;
    float wu_ = e1 ? y0 : s2;
    float wo_ = e1 ? y1 : s3;
    // gates (|input| <= 1: products of cosines)
    float fg = sigmoid_poly(wf_);
    float ig = sigmoid_poly(wi_);
    float ug = tanh_pade(wu_);
    float og = sigmoid_poly(wo_);
    c = fmaf(fg, c, ig * ug);
    h = og * tanh_pade(c);
    out[(size_t)t * pstr + gid] = h;
  };

  // depth-4 named prefetch pipeline
  float A0, A1, A2, B0, B1, B2, C0, C1, C2, D0, D1, D2;
  if (T > 0) ld3(0, A0, A1, A2);
  if (T > 1) ld3(1, B0, B1, B2);
  if (T > 2) ld3(2, C0, C1, C2);
  if (T > 3) ld3(3, D0, D1, D2);

  int T4 = T & ~3;
  for (int t = 0; t < T4; t += 4) {
    { float z0 = A0, z1 = A1, z2 = A2;
      if (t + 4 < T) ld3(t + 4, A0, A1, A2);
      step(z0, z1, z2, t); }
    { float z0 = B0, z1 = B1, z2 = B2;
      if (t + 5 < T) ld3(t + 5, B0, B1, B2);
      step(z0, z1, z2, t + 1); }
    { float z0 = C0, z1 = C1, z2 = C2;
      if (t + 6 < T) ld3(t + 6, C0, C1, C2);
      step(z0, z1, z2, t + 2); }
    { float z0 = D0, z1 = D1, z2 = D2;
      if (t + 7 < T) ld3(t + 7, D0, D1, D2);
      step(z0, z1, z2, t + 3); }
  }
  for (int t = T4; t < T; ++t) {
    float z0, z1, z2;
    ld3(t, z0, z1, z2);
    step(z0, z1, z2, t);
  }
  hx[gid]  = h;
  cxp[gid] = c;
}

// ---------------------------------------------------------------------------
// Fallback (only if workspace can't hold Z): fused, slow but correct.
// ---------------------------------------------------------------------------
struct GK {
  float wh[4][3][4];
  float ct1[4];
  float m2c[4];
};

__device__ __forceinline__ void load_gk(GK& K,
    const float* Wf, const float* Wi, const float* Wu, const float* Wo,
    const float* thf, const float* thi, const float* thu, const float* tho,
    int D)
{
  const float* Ws[4] = {Wf, Wi, Wu, Wo};
  const float* ts[4] = {thf, thi, thu, tho};
  const int ldw = D + 4;
#pragma unroll
  for (int g = 0; g < 4; ++g) {
#pragma unroll
    for (int jj = 0; jj < 3; ++jj) {
      int row = (jj == 2) ? 3 : jj;
#pragma unroll
      for (int qq = 0; qq < 4; ++qq)
        K.wh[g][jj][qq] = Ws[g][row * ldw + D + qq];
    }
    K.ct1[g] = fast_cos(ts[g][1]);
    K.m2c[g] = fast_cos(ts[g][2]);
  }
}

__device__ __forceinline__ void qlstm_step_sc(const float a[12], const GK& K,
                                              float h[4], float c[4])
{
  float gv[4][4];
#pragma unroll
  for (int g = 0; g < 4; ++g) {
    float m0 = fast_cos(a[g * 3 + 0]);
    float m1 = K.ct1[g] * fast_cos(a[g * 3 + 1]);
    float m3 = fast_cos(a[g * 3 + 2]);
    float m01 = m0 * m1;
    float m23 = K.m2c[g] * m3;
    gv[g][0] = m1 * m23;
    gv[g][1] = m01;
    gv[g][2] = m01 * K.m2c[g];
    gv[g][3] = m01 * m23;
  }
#pragma unroll
  for (int qq = 0; qq < 4; ++qq) {
    float fg = fast_sigmoid(gv[0][qq]);
    float ig = fast_sigmoid(gv[1][qq]);
    float ug = fast_tanh(gv[2][qq]);
    float og = fast_sigmoid(gv[3][qq]);
    c[qq] = fg * c[qq] + ig * ug;
    h[qq] = og * fast_tanh(c[qq]);
  }
}

__global__ __launch_bounds__(256) void qlstm_fused(
    const float* __restrict__ x,
    const float* __restrict__ Wf, const float* __restrict__ bf,
    const float* __restrict__ Wi, const float* __restrict__ bi,
    const float* __restrict__ Wu, const float* __restrict__ bu,
    const float* __restrict__ Wo, const float* __restrict__ bo,
    const float* __restrict__ thf, const float* __restrict__ thi,
    const float* __restrict__ thu, const float* __restrict__ tho,
    float* __restrict__ out, int T, int B, int D)
{
  int b = blockIdx.x * 256 + threadIdx.x;
  if (b >= B) return;
  GK K;
  load_gk(K, Wf, Wi, Wu, Wo, thf, thi, thu, tho, D);
  const float* Ws[4] = {Wf, Wi, Wu, Wo};
  const float* bs[4] = {bf, bi, bu, bo};
  const float* ts[4] = {thf, thi, thu, tho};
  const int ldw = D + 4;

  float base[12];
#pragma unroll
  for (int g = 0; g < 4; ++g) {
    base[g * 3 + 0] = bs[g][0] + ts[g][0];
    base[g * 3 + 1] = bs[g][1];
    base[g * 3 + 2] = bs[g][3] + ts[g][3];
  }

  float h[4] = {0.f, 0.f, 0.f, 0.f};
  float c[4] = {0.f, 0.f, 0.f, 0.f};
  float* hx  = out + (size_t)T * B * 4;
  float* cxp = hx + (size_t)B * 4;

  for (int t = 0; t < T; ++t) {
    float a[12];
#pragma unroll
    for (int j = 0; j < 12; ++j) a[j] = base[j];
    const float* xp = x + ((size_t)t * B + b) * D;
    for (int k = 0; k < D; k += 4) {
      float4 xv = *(const float4*)(xp + k);
#pragma unroll
      for (int g = 0; g < 4; ++g) {
        const float* W = Ws[g];
#pragma unroll
        for (int jj = 0; jj < 3; ++jj) {
          int row = (jj == 2) ? 3 : jj;
          const float* wp = W + row * ldw + k;
          a[g * 3 + jj] += xv.x * wp[0] + xv.y * wp[1] + xv.z * wp[2] + xv.w * wp[3];
        }
      }
    }
#pragma unroll
    for (int g = 0; g < 4; ++g) {
#pragma unroll
      for (int jj = 0; jj < 3; ++jj) {
        a[g * 3 + jj] += K.wh[g][jj][0] * h[0] + K.wh[g][jj][1] * h[1]
                       + K.wh[g][jj][2] * h[2] + K.wh[g][jj][3] * h[3];
      }
    }
    qlstm_step_sc(a, K, h, c);
    *(float4*)(out + ((size_t)t * B + b) * 4) = make_float4(h[0], h[1], h[2], h[3]);
  }
  *(float4*)(hx + (size_t)b * 4)  = make_float4(h[0], h[1], h[2], h[3]);
  *(float4*)(cxp + (size_t)b * 4) = make_float4(c[0], c[1], c[2], c[3]);
}

// ---------------------------------------------------------------------------
extern "C" void kernel_launch(void* const* d_in, const int* in_sizes, int n_in,
                              void* d_out, int out_size, void* d_ws, size_t ws_size,
                              hipStream_t stream)
{
  const float* x   = (const float*)d_in[0];
  const float* Wf  = (const float*)d_in[1];
  const float* bf  = (const float*)d_in[2];
  const float* Wi  = (const float*)d_in[3];
  const float* bi  = (const float*)d_in[4];
  const float* Wu  = (const float*)d_in[5];
  const float* bu  = (const float*)d_in[6];
  const float* Wo  = (const float*)d_in[7];
  const float* bo  = (const float*)d_in[8];
  const float* thf = (const float*)d_in[9];
  const float* thi = (const float*)d_in[10];
  const float* thu = (const float*)d_in[11];
  const float* tho = (const float*)d_in[12];

  int DH = in_sizes[1] / 4;                 // D + H (H = 4)
  int D  = DH - 4;                          // 128
  long long TB = (long long)in_sizes[0] / D;          // T*B
  int B = (int)(((long long)out_size - 4 * TB) / 8);  // out = 4*T*B + 8*B
  int T = (int)(TB / B);

  size_t zbytes = (size_t)TB * 12 * sizeof(float);
  if (ws_size >= zbytes && (D & 31) == 0) {
    float* Z = (float*)d_ws;
    int gblocks = (int)((TB + 63) / 64);
    qlstm_gemm<<<gblocks, 64, 0, stream>>>(x, Wf, bf, Wi, bi, Wu, bu, Wo, bo,
                                           thf, thi, thu, tho, Z, TB, B, D);
    int sthreads = B * 4;
    qlstm_scan4<<<(sthreads + 63) / 64, 64, 0, stream>>>(Z, Wf, Wi, Wu, Wo,
                                                         thf, thi, thu, tho,
                                                         (float*)d_out, T, B, D);
  } else {
    qlstm_fused<<<(B + 255) / 256, 256, 0, stream>>>(x, Wf, bf, Wi, bi, Wu, bu, Wo, bo,
                                                     thf, thi, thu, tho,
                                                     (float*)d_out, T, B, D);
  }
}